// Round 18
// baseline (259.270 us; speedup 1.0000x reference)
//
#include <hip/hip_runtime.h>
#include <hip/hip_bf16.h>

// B=1, S=256 (attention/LN axis), R=256, C=256, H=8, D=32.
// Round 18: flash_proj reverted to the r16 form EXACTLY (r17's reg-prefetch
// pushed VGPR 56->68, crossing the 64-reg occupancy cliff: 36%->22%, dur
// 117->145 us. Rule: stay <=64 VGPRs in the latency-bound flash kernel).
// qkvg restructured to CHUNKED x (4 chunks of 64 rows, 32 KB tile instead of
// the 128 KB full tile): KV j-tile jt only needs rows [32jt,32jt+32) and
// Q/G i-tile it only rows [16it,16it+16), so LDS drops 133->34 KB ->
// 4 blocks/CU co-resident (was 1) for 4x latency hiding. Math, stores and
// swizzle bit-identical to r16. All builtins, no inline asm.

using f32x4  = __attribute__((ext_vector_type(4))) float;
using bf16x8 = __attribute__((ext_vector_type(8))) short;

struct U4x { unsigned a0, a1, a2, a3; };
static_assert(sizeof(U4x) == sizeof(bf16x8), "frag size");

__device__ __forceinline__ f32x4 mfma16(bf16x8 a, bf16x8 b, f32x4 c){
  return __builtin_amdgcn_mfma_f32_16x16x32_bf16(a, b, c, 0, 0, 0);
}
// f32 -> bf16 RNE, finite inputs only.
__device__ __forceinline__ unsigned f2bf(float f){
  unsigned u = __builtin_bit_cast(unsigned, f);
  u += 0x7fffu + ((u >> 16) & 1u);
  return u >> 16;
}
__device__ __forceinline__ unsigned pk2(float lo, float hi){
  return f2bf(lo) | (f2bf(hi) << 16);
}
__device__ __forceinline__ bf16x8 mk_frag(unsigned a0, unsigned a1, unsigned a2, unsigned a3){
  U4x t{a0, a1, a2, a3};
  return __builtin_bit_cast(bf16x8, t);
}
__device__ __forceinline__ float sigm(float x){ return 1.f / (1.f + __expf(-x)); }

// Swizzled byte address in a [rows][256 bf16] LDS tile (row stride 512B).
__device__ __forceinline__ int xaddr(int row, int cbyte){
  return (row << 9) + (cbyte ^ ((row & 15) << 4));
}
__device__ __forceinline__ bf16x8 lds_frag(const char* sm, int row, int cshort){
  return *(const bf16x8*)(sm + xaddr(row, cshort * 2));
}
__device__ __forceinline__ bf16x8 ldg_frag(const short* base, int row, int cshort){
  return *(const bf16x8*)(base + row * 256 + cshort);
}
__device__ __forceinline__ void store_go(char* sm, int i0, int hd, unsigned v0, unsigned v1){
  *(short*)(sm + xaddr(i0 + 0, hd * 2)) = (short)(v0 & 0xffffu);
  *(short*)(sm + xaddr(i0 + 1, hd * 2)) = (short)(v0 >> 16);
  *(short*)(sm + xaddr(i0 + 2, hd * 2)) = (short)(v1 & 0xffffu);
  *(short*)(sm + xaddr(i0 + 3, hd * 2)) = (short)(v1 >> 16);
}

// ---------------- prep: transpose + bf16-convert the 5 weight matrices -----
// ws (shorts): WqT[256][256], WkT, WvT, WgT  (T[n][c] = W[c][n], n = h*32+d)
//              WoT[256][256]                 (WoT[c][hd] = Wo[hd][c])
__global__ __launch_bounds__(256) void prep_weights(
    const float* __restrict__ Wq, const float* __restrict__ Wk,
    const float* __restrict__ Wv, const float* __restrict__ Wg,
    const float* __restrict__ Wo, short* __restrict__ ws)
{
  const int n = blockIdx.x, t = threadIdx.x;
  ws[0*65536 + n*256 + t] = (short)f2bf(Wq[t*256 + n]);
  ws[1*65536 + n*256 + t] = (short)f2bf(Wk[t*256 + n]);
  ws[2*65536 + n*256 + t] = (short)f2bf(Wv[t*256 + n]);
  ws[3*65536 + n*256 + t] = (short)f2bf(Wg[t*256 + n]);
  ws[4*65536 + n*256 + t] = (short)f2bf(Wo[t*256 + n]);
}

// ---------------- stage 2: LN + QKVG frags, CHUNKED x (34 KB LDS) ----------
// kvF: uint4 [r][head][jt(8)][4:{kf0,kf1,vf0,vf1}][lane]        (67.1 MB)
// qF : uint2 [r][head][it(16)][dr(2)][lane]                     (33.6 MB)
// gF : uint4(f32x4) [r][head][it(16)][dr(2)][lane]              (67.1 MB)
__global__ __launch_bounds__(512) void msa_qkvg(
    const float* __restrict__ msa, const float* __restrict__ lnw,
    const float* __restrict__ lnb, const float* __restrict__ bg,
    const short* __restrict__ wsW,
    uint4* __restrict__ kvF, uint2* __restrict__ qF, uint4* __restrict__ gF)
{
  extern __shared__ __align__(16) char sm[];   // [0,32768): 64-row x chunk
  float* muA = (float*)(sm + 32768);           // 256 f32
  float* rsA = muA + 256;                      // 256 f32
  const int r   = blockIdx.x;
  const int tid = threadIdx.x;
  const float* msa_r = msa + r * 256;

  // ---- LN stats over s for each c (identical math to r13-r16) ----
  {
    float s0 = 0.f, s1 = 0.f;
    const int c = tid & 255, sh = tid >> 8;
    const float* p = msa_r + (sh * 128) * 65536 + c;
    #pragma unroll 8
    for (int i = 0; i < 128; i++){ float v = p[i * 65536]; s0 += v; s1 += v * v; }
    float* sb = (float*)sm;                    // transient, inside x region
    sb[tid] = s0; sb[512 + tid] = s1;
    __syncthreads();
    if (tid < 256){
      float tot = sb[tid] + sb[256 + tid];
      float sq  = sb[512 + tid] + sb[768 + tid];
      float mu  = tot * (1.f / 256.f);
      float var = fmaxf(sq * (1.f / 256.f) - mu * mu, 0.f);
      muA[tid] = mu; rsA[tid] = rsqrtf(var + 1e-5f);
    }
    __syncthreads();
  }

  const int wid  = tid >> 6;                   // head
  const int lane = tid & 63;
  const int g = lane >> 4, c15 = lane & 15;
  const short* WqT = wsW;
  const short* WkT = wsW + 65536;
  const short* WvT = wsW + 2 * 65536;
  const short* WgT = wsW + 3 * 65536;
  const int hbase = wid * 32;
  const float bg0 = bg[hbase + c15], bg1 = bg[hbase + 16 + c15];
  const float scl = 0.17677669529663687f * 1.4426950408889634f; // /sqrt(32)*log2e
  const f32x4 zz{0.f, 0.f, 0.f, 0.f};

  const int c0 = (tid & 31) * 8;
  float mu0[8], rs0[8];
  #pragma unroll
  for (int k = 0; k < 8; k++){ mu0[k] = muA[c0 + k]; rs0[k] = rsA[c0 + k]; }

  // ---- 4 chunks of 64 x-rows; per chunk: build x, 2 KV j-tiles, 4 Q/G ----
  #pragma unroll 1
  for (int ch = 0; ch < 4; ch++){
    // build x rows [ch*64, ch*64+64) into local rows [0,64)
    #pragma unroll
    for (int itr = 0; itr < 4; itr++){
      const int lr = itr * 16 + (tid >> 5);    // local row 0..63
      const int s  = ch * 64 + lr;
      const float w = lnw[s], b = lnb[s];
      const float* rp = msa_r + s * 65536 + c0;
      f32x4 v0 = *(const f32x4*)rp;
      f32x4 v1 = *(const f32x4*)(rp + 4);
      U4x q{pk2((v0.x-mu0[0])*rs0[0]*w+b, (v0.y-mu0[1])*rs0[1]*w+b),
            pk2((v0.z-mu0[2])*rs0[2]*w+b, (v0.w-mu0[3])*rs0[3]*w+b),
            pk2((v1.x-mu0[4])*rs0[4]*w+b, (v1.y-mu0[5])*rs0[5]*w+b),
            pk2((v1.z-mu0[6])*rs0[6]*w+b, (v1.w-mu0[7])*rs0[7]*w+b)};
      *(U4x*)(sm + xaddr(lr, c0 * 2)) = q;
    }
    __syncthreads();

    // K^T / V fragments for the chunk's 2 j-tiles
    #pragma unroll 1
    for (int j2 = 0; j2 < 2; j2++){
      const int jt = ch * 2 + j2;              // global j-tile
      const int jb = j2 * 32;                  // local row base
      f32x4 kt00=zz, kt01=zz, kt10=zz, kt11=zz;
      f32x4 va00=zz, va01=zz, va10=zz, va11=zz;
      #pragma unroll
      for (int kk = 0; kk < 8; kk++){
        const int cs = 32*kk + 8*g;
        bf16x8 wk0 = ldg_frag(WkT, hbase + c15,      cs);
        bf16x8 wk1 = ldg_frag(WkT, hbase + 16 + c15, cs);
        bf16x8 wv0 = ldg_frag(WvT, hbase + c15,      cs);
        bf16x8 wv1 = ldg_frag(WvT, hbase + 16 + c15, cs);
        bf16x8 bx0 = lds_frag(sm, jb + c15,      cs);
        bf16x8 bx1 = lds_frag(sm, jb + 16 + c15, cs);
        kt00 = mfma16(wk0, bx0, kt00);   // K^T[d 0:16 ][j 0:16 ]
        kt01 = mfma16(wk0, bx1, kt01);   // K^T[d 0:16 ][j 16:32]
        kt10 = mfma16(wk1, bx0, kt10);   // K^T[d 16:32][j 0:16 ]
        kt11 = mfma16(wk1, bx1, kt11);   // K^T[d 16:32][j 16:32]
        va00 = mfma16(bx0, wv0, va00);   // V[j 0:16 ][d 0:16 ]
        va01 = mfma16(bx0, wv1, va01);   // V[j 0:16 ][d 16:32]
        va10 = mfma16(bx1, wv0, va10);   // V[j 16:32][d 0:16 ]
        va11 = mfma16(bx1, wv1, va11);   // V[j 16:32][d 16:32]
      }
      const bf16x8 kf0 = mk_frag(pk2(kt00.x,kt00.y), pk2(kt00.z,kt00.w),
                                 pk2(kt10.x,kt10.y), pk2(kt10.z,kt10.w));
      const bf16x8 kf1 = mk_frag(pk2(kt01.x,kt01.y), pk2(kt01.z,kt01.w),
                                 pk2(kt11.x,kt11.y), pk2(kt11.z,kt11.w));
      const bf16x8 vf0 = mk_frag(pk2(va00.x,va00.y), pk2(va00.z,va00.w),
                                 pk2(va10.x,va10.y), pk2(va10.z,va10.w));
      const bf16x8 vf1 = mk_frag(pk2(va01.x,va01.y), pk2(va01.z,va01.w),
                                 pk2(va11.x,va11.y), pk2(va11.z,va11.w));
      const size_t kb = ((size_t)(r*64 + wid*8 + jt) * 4) * 64 + lane;
      kvF[kb      ] = __builtin_bit_cast(uint4, kf0);
      kvF[kb +  64] = __builtin_bit_cast(uint4, kf1);
      kvF[kb + 128] = __builtin_bit_cast(uint4, vf0);
      kvF[kb + 192] = __builtin_bit_cast(uint4, vf1);
    }

    // Q^T fragments (scaled) for the chunk's 4 i-tiles
    #pragma unroll 1
    for (int dr = 0; dr < 2; dr++){
      bf16x8 wq[8];
      #pragma unroll
      for (int kk = 0; kk < 8; kk++) wq[kk] = ldg_frag(WqT, hbase + 16*dr + c15, 32*kk + 8*g);
      #pragma unroll
      for (int nt = 0; nt < 4; nt++){
        f32x4 a = zz;
        #pragma unroll
        for (int kk = 0; kk < 8; kk++)
          a = mfma16(wq[kk], lds_frag(sm, nt*16 + c15, 32*kk + 8*g), a);
        const int it = ch * 4 + nt;            // global i-tile
        uint2 qv; qv.x = pk2(a.x*scl, a.y*scl); qv.y = pk2(a.z*scl, a.w*scl);
        qF[(((size_t)(r*8 + wid)*16 + it)*2 + dr)*64 + lane] = qv;
      }
    }

    // G fragments (sigmoid, f32) for the chunk's 4 i-tiles
    #pragma unroll 1
    for (int dr = 0; dr < 2; dr++){
      bf16x8 wg[8];
      #pragma unroll
      for (int kk = 0; kk < 8; kk++) wg[kk] = ldg_frag(WgT, hbase + 16*dr + c15, 32*kk + 8*g);
      const float bgd = dr ? bg1 : bg0;
      #pragma unroll
      for (int nt = 0; nt < 4; nt++){
        f32x4 a = zz;
        #pragma unroll
        for (int kk = 0; kk < 8; kk++)
          a = mfma16(lds_frag(sm, nt*16 + c15, 32*kk + 8*g), wg[kk], a);
        const int it = ch * 4 + nt;
        f32x4 ga; ga.x = sigm(a.x + bgd); ga.y = sigm(a.y + bgd);
        ga.z = sigm(a.z + bgd); ga.w = sigm(a.w + bgd);
        gF[(((size_t)(r*8 + wid)*16 + it)*2 + dr)*64 + lane] = __builtin_bit_cast(uint4, ga);
      }
    }
    __syncthreads();   // chunk's x rows dead before next overwrite
  }
}

// ---------------- stage 3: flash + gate + out-projection (r16 EXACT) -------
// XCD-aware mapping: xcd = blk&7, s = blk>>3 -> r = xcd*32 + (s>>2), chq=s&3.
__global__ __launch_bounds__(512) void msa_flash_proj(
    const uint4* __restrict__ kvF, const uint2* __restrict__ qF,
    const uint4* __restrict__ gF,  const short* __restrict__ WoT,
    const float* __restrict__ bo,  float* __restrict__ out)
{
  __shared__ __align__(16) char sm[32768];     // GO tile: 64 rows x 256 bf16
  const int tid  = threadIdx.x;
  const int h    = tid >> 6;                   // wave = head
  const int lane = tid & 63;
  const int g = lane >> 4, c15 = lane & 15;
  const int blk = blockIdx.x;                  // 0..1023
  const int xcd = blk & 7, s8 = blk >> 3;
  const int r = xcd * 32 + (s8 >> 2), chq = s8 & 3;
  const int hbase = h * 32;
  const int ib = chq * 64;
  const f32x4 zz{0.f, 0.f, 0.f, 0.f};

  bf16x8 bSq[4];
  #pragma unroll
  for (int nt = 0; nt < 4; nt++){
    const size_t qb = (((size_t)(r*8 + h)*16 + (ib >> 4) + nt)*2)*64 + lane;
    uint2 qlo = qF[qb], qhi = qF[qb + 64];
    bSq[nt] = mk_frag(qlo.x, qlo.y, qhi.x, qhi.y);
  }

  float l_[4];
  f32x4 o_[4][2];
  #pragma unroll
  for (int i2 = 0; i2 < 4; i2++){ l_[i2] = 0.f; o_[i2][0] = zz; o_[i2][1] = zz; }

  #pragma unroll 2
  for (int jt = 0; jt < 8; jt++){
    const size_t kb = ((size_t)(r*64 + h*8 + jt) * 4) * 64 + lane;
    const bf16x8 kf0 = __builtin_bit_cast(bf16x8, kvF[kb      ]);
    const bf16x8 kf1 = __builtin_bit_cast(bf16x8, kvF[kb +  64]);
    const bf16x8 vf0 = __builtin_bit_cast(bf16x8, kvF[kb + 128]);
    const bf16x8 vf1 = __builtin_bit_cast(bf16x8, kvF[kb + 192]);
    #pragma unroll
    for (int it = 0; it < 4; it++){
      f32x4 s0 = mfma16(kf0, bSq[it], zz);   // S[i=c15][j=32jt+4g+jj]
      f32x4 s1 = mfma16(kf1, bSq[it], zz);   // S[i=c15][j=32jt+16+4g+jj]
      float e0=exp2f(s0.x), e1=exp2f(s0.y), e2=exp2f(s0.z), e3=exp2f(s0.w);
      float e4=exp2f(s1.x), e5=exp2f(s1.y), e6=exp2f(s1.z), e7=exp2f(s1.w);
      l_[it] += ((e0+e1)+(e2+e3)) + ((e4+e5)+(e6+e7));
      bf16x8 aP = mk_frag(pk2(e0,e1), pk2(e2,e3), pk2(e4,e5), pk2(e6,e7));
      o_[it][0] = mfma16(aP, vf0, o_[it][0]);
      o_[it][1] = mfma16(aP, vf1, o_[it][1]);
    }
  }

  #pragma unroll
  for (int dr = 0; dr < 2; dr++){
    #pragma unroll
    for (int nt = 0; nt < 4; nt++){
      f32x4 ga = __builtin_bit_cast(f32x4,
          gF[(((size_t)(r*8 + h)*16 + (ib >> 4) + nt)*2 + dr)*64 + lane]);
      float lt = l_[nt];
      lt += __shfl_xor(lt, 16); lt += __shfl_xor(lt, 32);
      float inv[4];
      #pragma unroll
      for (int jj = 0; jj < 4; jj++) inv[jj] = 1.f / __shfl(lt, 4*g + jj);
      const f32x4 ov = o_[nt][dr];
      const unsigned w0 = pk2(ov[0]*inv[0]*ga.x, ov[1]*inv[1]*ga.y);
      const unsigned w1 = pk2(ov[2]*inv[2]*ga.z, ov[3]*inv[3]*ga.w);
      store_go(sm, nt*16 + 4*g, hbase + 16*dr + c15, w0, w1);
    }
  }
  __syncthreads();

  const int it2 = h & 3;
  const int cth = (h >> 2) * 8;
  bf16x8 aGO[8];
  #pragma unroll
  for (int kk = 0; kk < 8; kk++) aGO[kk] = lds_frag(sm, it2*16 + c15, 32*kk + 8*g);
  #pragma unroll 2
  for (int c8 = 0; c8 < 8; c8++){
    const int ct = cth + c8;
    f32x4 acc = zz;
    #pragma unroll
    for (int kk = 0; kk < 8; kk++)
      acc = mfma16(aGO[kk], ldg_frag(WoT, ct*16 + c15, 32*kk + 8*g), acc);
    const float bov = bo[ct*16 + c15];
    const int i0 = ib + it2*16 + g*4;
    const int cc = ct*16 + c15;
    out[(size_t)(i0 + 0) * 65536 + r * 256 + cc] = acc.x + bov;
    out[(size_t)(i0 + 1) * 65536 + r * 256 + cc] = acc.y + bov;
    out[(size_t)(i0 + 2) * 65536 + r * 256 + cc] = acc.z + bov;
    out[(size_t)(i0 + 3) * 65536 + r * 256 + cc] = acc.w + bov;
  }
}

// ---------------------------------------------------------------------------
extern "C" void kernel_launch(void* const* d_in, const int* in_sizes, int n_in,
                              void* d_out, int out_size, void* d_ws, size_t ws_size,
                              hipStream_t stream)
{
  (void)in_sizes; (void)n_in; (void)out_size; (void)ws_size;
  const float* msa = (const float*)d_in[0];
  const float* lnw = (const float*)d_in[1];
  const float* lnb = (const float*)d_in[2];
  const float* Wq  = (const float*)d_in[3];
  const float* Wk  = (const float*)d_in[4];
  const float* Wv  = (const float*)d_in[5];
  const float* Wg  = (const float*)d_in[6];
  const float* bg  = (const float*)d_in[7];
  const float* Wo  = (const float*)d_in[8];
  const float* bo  = (const float*)d_in[9];
  short* ws = (short*)d_ws;
  char* base = (char*)d_ws;

  prep_weights<<<256, 256, 0, stream>>>(Wq, Wk, Wv, Wg, Wo, ws);

  const size_t WB  = (size_t)5 * 65536 * 2;          //  0.66 MB weights
  const size_t KVB = (size_t)256*8*8*4*64 * 16;      // 67.11 MB K/V frags
  const size_t QB  = (size_t)256*8*16*2*64 * 8;      // 33.55 MB Q frags

  uint4* kvF = (uint4*)(base + WB);
  uint2* qF  = (uint2*)(base + WB + KVB);
  uint4* gF  = (uint4*)(base + WB + KVB + QB);
  msa_qkvg      <<<256, 512, 34816, stream>>>(msa, lnw, lnb, bg, ws, kvF, qF, gF);
  msa_flash_proj<<<1024, 512, 0, stream>>>(kvF, qF, gF, ws + 4*65536, bo, (float*)d_out);
}

// Round 19
// 179.941 us; speedup vs baseline: 1.4409x; 1.4409x over previous
//
#include <hip/hip_runtime.h>
#include <hip/hip_bf16.h>

// B=1, S=256 (attention/LN axis), R=256, C=256, H=8, D=32.
// Round 19: RESTORE round-16 verbatim — the session's best passing kernel
// (180.5 us). r17 (reg-prefetch) crossed the 64-VGPR occupancy cliff
// (56->68 regs, 117->145 us); r18 (LDS-chunked qkvg) crossed the 128-VGPR
// spill cliff (100->128 regs, +78 MB spill, 75->153 us). Both cliffs bound
// this structure tightly; r16 sits between them with zero spill in both
// kernels. Pipeline: prep_weights -> msa_qkvg (LN + QKVG frags, 100 VGPR)
// -> msa_flash_proj (flash + gate + out-proj, 56 VGPR, XCD-swizzled).
// All builtins, no inline asm.

using f32x4  = __attribute__((ext_vector_type(4))) float;
using bf16x8 = __attribute__((ext_vector_type(8))) short;

struct U4x { unsigned a0, a1, a2, a3; };
static_assert(sizeof(U4x) == sizeof(bf16x8), "frag size");

__device__ __forceinline__ f32x4 mfma16(bf16x8 a, bf16x8 b, f32x4 c){
  return __builtin_amdgcn_mfma_f32_16x16x32_bf16(a, b, c, 0, 0, 0);
}
// f32 -> bf16 RNE, finite inputs only.
__device__ __forceinline__ unsigned f2bf(float f){
  unsigned u = __builtin_bit_cast(unsigned, f);
  u += 0x7fffu + ((u >> 16) & 1u);
  return u >> 16;
}
__device__ __forceinline__ unsigned pk2(float lo, float hi){
  return f2bf(lo) | (f2bf(hi) << 16);
}
__device__ __forceinline__ bf16x8 mk_frag(unsigned a0, unsigned a1, unsigned a2, unsigned a3){
  U4x t{a0, a1, a2, a3};
  return __builtin_bit_cast(bf16x8, t);
}
__device__ __forceinline__ float sigm(float x){ return 1.f / (1.f + __expf(-x)); }

// Swizzled byte address in a [rows][256 bf16] LDS tile (row stride 512B).
__device__ __forceinline__ int xaddr(int row, int cbyte){
  return (row << 9) + (cbyte ^ ((row & 15) << 4));
}
__device__ __forceinline__ bf16x8 lds_frag(const char* sm, int row, int cshort){
  return *(const bf16x8*)(sm + xaddr(row, cshort * 2));
}
__device__ __forceinline__ bf16x8 ldg_frag(const short* base, int row, int cshort){
  return *(const bf16x8*)(base + row * 256 + cshort);
}
__device__ __forceinline__ void store_go(char* sm, int i0, int hd, unsigned v0, unsigned v1){
  *(short*)(sm + xaddr(i0 + 0, hd * 2)) = (short)(v0 & 0xffffu);
  *(short*)(sm + xaddr(i0 + 1, hd * 2)) = (short)(v0 >> 16);
  *(short*)(sm + xaddr(i0 + 2, hd * 2)) = (short)(v1 & 0xffffu);
  *(short*)(sm + xaddr(i0 + 3, hd * 2)) = (short)(v1 >> 16);
}

// ---------------- prep: transpose + bf16-convert the 5 weight matrices -----
// ws (shorts): WqT[256][256], WkT, WvT, WgT  (T[n][c] = W[c][n], n = h*32+d)
//              WoT[256][256]                 (WoT[c][hd] = Wo[hd][c])
__global__ __launch_bounds__(256) void prep_weights(
    const float* __restrict__ Wq, const float* __restrict__ Wk,
    const float* __restrict__ Wv, const float* __restrict__ Wg,
    const float* __restrict__ Wo, short* __restrict__ ws)
{
  const int n = blockIdx.x, t = threadIdx.x;
  ws[0*65536 + n*256 + t] = (short)f2bf(Wq[t*256 + n]);
  ws[1*65536 + n*256 + t] = (short)f2bf(Wk[t*256 + n]);
  ws[2*65536 + n*256 + t] = (short)f2bf(Wv[t*256 + n]);
  ws[3*65536 + n*256 + t] = (short)f2bf(Wg[t*256 + n]);
  ws[4*65536 + n*256 + t] = (short)f2bf(Wo[t*256 + n]);
}

// ---------------- phase 1: LN stats + normalized x tile (512 threads) ------
__device__ __forceinline__ void build_x_tile_512(
    char* sm, const float* msa_r, const float* lnw, const float* lnb, int tid)
{
  float* muA = (float*)(sm + 131072);
  float* rsA = muA + 256;
  {
    float s0 = 0.f, s1 = 0.f;
    const int c = tid & 255, sh = tid >> 8;
    const float* p = msa_r + (sh * 128) * 65536 + c;
    #pragma unroll 8
    for (int i = 0; i < 128; i++){ float v = p[i * 65536]; s0 += v; s1 += v * v; }
    float* sb = (float*)sm;
    sb[tid] = s0; sb[512 + tid] = s1;
    __syncthreads();
    if (tid < 256){
      float tot = sb[tid] + sb[256 + tid];
      float sq  = sb[512 + tid] + sb[768 + tid];
      float mu  = tot * (1.f / 256.f);
      float var = fmaxf(sq * (1.f / 256.f) - mu * mu, 0.f);
      muA[tid] = mu; rsA[tid] = rsqrtf(var + 1e-5f);
    }
    __syncthreads();
  }
  {
    const int c0 = (tid & 31) * 8;
    float mu0[8], rs0[8];
    #pragma unroll
    for (int k = 0; k < 8; k++){ mu0[k] = muA[c0 + k]; rs0[k] = rsA[c0 + k]; }
    for (int itr = 0; itr < 16; itr++){
      const int s = itr * 16 + (tid >> 5);
      const float w = lnw[s], b = lnb[s];
      const float* rp = msa_r + s * 65536 + c0;
      f32x4 v0 = *(const f32x4*)rp;
      f32x4 v1 = *(const f32x4*)(rp + 4);
      U4x q{pk2((v0.x-mu0[0])*rs0[0]*w+b, (v0.y-mu0[1])*rs0[1]*w+b),
            pk2((v0.z-mu0[2])*rs0[2]*w+b, (v0.w-mu0[3])*rs0[3]*w+b),
            pk2((v1.x-mu0[4])*rs0[4]*w+b, (v1.y-mu0[5])*rs0[5]*w+b),
            pk2((v1.z-mu0[6])*rs0[6]*w+b, (v1.w-mu0[7])*rs0[7]*w+b)};
      *(U4x*)(sm + xaddr(s, c0 * 2)) = q;
    }
    __syncthreads();
  }
}

// ---------------- stage 2: LN + QKVG fragment generation (r13-proven) ------
// kvF: uint4 [r][head][jt(8)][4:{kf0,kf1,vf0,vf1}][lane]        (67.1 MB)
// qF : uint2 [r][head][it(16)][dr(2)][lane]                     (33.6 MB)
// gF : uint4(f32x4) [r][head][it(16)][dr(2)][lane]              (67.1 MB)
__global__ __launch_bounds__(512) void msa_qkvg(
    const float* __restrict__ msa, const float* __restrict__ lnw,
    const float* __restrict__ lnb, const float* __restrict__ bg,
    const short* __restrict__ wsW,
    uint4* __restrict__ kvF, uint2* __restrict__ qF, uint4* __restrict__ gF)
{
  extern __shared__ __align__(16) char sm[];
  const int r   = blockIdx.x;
  const int tid = threadIdx.x;
  build_x_tile_512(sm, msa + r * 256, lnw, lnb, tid);

  const int wid  = tid >> 6;                   // head
  const int lane = tid & 63;
  const int g = lane >> 4, c15 = lane & 15;
  const short* WqT = wsW;
  const short* WkT = wsW + 65536;
  const short* WvT = wsW + 2 * 65536;
  const short* WgT = wsW + 3 * 65536;
  const int hbase = wid * 32;
  const float bg0 = bg[hbase + c15], bg1 = bg[hbase + 16 + c15];
  const float scl = 0.17677669529663687f * 1.4426950408889634f; // /sqrt(32)*log2e
  const f32x4 zz{0.f, 0.f, 0.f, 0.f};

  // ---- K^T / V fragments per j-tile (accumulators die into stores) ----
  #pragma unroll 1
  for (int jt = 0; jt < 8; jt++){
    const int jb = jt * 32;
    f32x4 kt00=zz, kt01=zz, kt10=zz, kt11=zz;
    f32x4 va00=zz, va01=zz, va10=zz, va11=zz;
    #pragma unroll
    for (int kk = 0; kk < 8; kk++){
      const int cs = 32*kk + 8*g;
      bf16x8 wk0 = ldg_frag(WkT, hbase + c15,      cs);
      bf16x8 wk1 = ldg_frag(WkT, hbase + 16 + c15, cs);
      bf16x8 wv0 = ldg_frag(WvT, hbase + c15,      cs);
      bf16x8 wv1 = ldg_frag(WvT, hbase + 16 + c15, cs);
      bf16x8 bx0 = lds_frag(sm, jb + c15,      cs);
      bf16x8 bx1 = lds_frag(sm, jb + 16 + c15, cs);
      kt00 = mfma16(wk0, bx0, kt00);   // K^T[d 0:16 ][j 0:16 ]
      kt01 = mfma16(wk0, bx1, kt01);   // K^T[d 0:16 ][j 16:32]
      kt10 = mfma16(wk1, bx0, kt10);   // K^T[d 16:32][j 0:16 ]
      kt11 = mfma16(wk1, bx1, kt11);   // K^T[d 16:32][j 16:32]
      va00 = mfma16(bx0, wv0, va00);   // V[j 0:16 ][d 0:16 ]
      va01 = mfma16(bx0, wv1, va01);   // V[j 0:16 ][d 16:32]
      va10 = mfma16(bx1, wv0, va10);   // V[j 16:32][d 0:16 ]
      va11 = mfma16(bx1, wv1, va11);   // V[j 16:32][d 16:32]
    }
    const bf16x8 kf0 = mk_frag(pk2(kt00.x,kt00.y), pk2(kt00.z,kt00.w),
                               pk2(kt10.x,kt10.y), pk2(kt10.z,kt10.w));
    const bf16x8 kf1 = mk_frag(pk2(kt01.x,kt01.y), pk2(kt01.z,kt01.w),
                               pk2(kt11.x,kt11.y), pk2(kt11.z,kt11.w));
    const bf16x8 vf0 = mk_frag(pk2(va00.x,va00.y), pk2(va00.z,va00.w),
                               pk2(va10.x,va10.y), pk2(va10.z,va10.w));
    const bf16x8 vf1 = mk_frag(pk2(va01.x,va01.y), pk2(va01.z,va01.w),
                               pk2(va11.x,va11.y), pk2(va11.z,va11.w));
    const size_t kb = ((size_t)(r*64 + wid*8 + jt) * 4) * 64 + lane;
    kvF[kb      ] = __builtin_bit_cast(uint4, kf0);
    kvF[kb +  64] = __builtin_bit_cast(uint4, kf1);
    kvF[kb + 128] = __builtin_bit_cast(uint4, vf0);
    kvF[kb + 192] = __builtin_bit_cast(uint4, vf1);
  }

  // ---- Q^T fragments (scaled), per (dr, it) ----
  #pragma unroll 1
  for (int dr = 0; dr < 2; dr++){
    bf16x8 wq[8];
    #pragma unroll
    for (int kk = 0; kk < 8; kk++) wq[kk] = ldg_frag(WqT, hbase + 16*dr + c15, 32*kk + 8*g);
    #pragma unroll 1
    for (int it = 0; it < 16; it++){
      f32x4 a = zz;
      #pragma unroll
      for (int kk = 0; kk < 8; kk++)
        a = mfma16(wq[kk], lds_frag(sm, it*16 + c15, 32*kk + 8*g), a);
      uint2 qv; qv.x = pk2(a.x*scl, a.y*scl); qv.y = pk2(a.z*scl, a.w*scl);
      qF[(((size_t)(r*8 + wid)*16 + it)*2 + dr)*64 + lane] = qv;
    }
  }

  // ---- G fragments (sigmoid applied, kept f32 for accuracy) ----
  #pragma unroll 1
  for (int dr = 0; dr < 2; dr++){
    bf16x8 wg[8];
    #pragma unroll
    for (int kk = 0; kk < 8; kk++) wg[kk] = ldg_frag(WgT, hbase + 16*dr + c15, 32*kk + 8*g);
    const float bgd = dr ? bg1 : bg0;
    #pragma unroll 1
    for (int it = 0; it < 16; it++){
      f32x4 a = zz;
      #pragma unroll
      for (int kk = 0; kk < 8; kk++)
        a = mfma16(lds_frag(sm, it*16 + c15, 32*kk + 8*g), wg[kk], a);
      f32x4 ga; ga.x = sigm(a.x + bgd); ga.y = sigm(a.y + bgd);
      ga.z = sigm(a.z + bgd); ga.w = sigm(a.w + bgd);
      gF[(((size_t)(r*8 + wid)*16 + it)*2 + dr)*64 + lane] = __builtin_bit_cast(uint4, ga);
    }
  }
}

// ---------------- stage 3: flash + gate + out-projection (fused) -----------
// XCD-aware mapping: xcd = blk&7, s = blk>>3 -> r = xcd*32 + (s>>2), chq=s&3.
// All 4 chq-blocks of an r share blockIdx mod 8 -> same XCD -> kvF L2-hot.
__global__ __launch_bounds__(512) void msa_flash_proj(
    const uint4* __restrict__ kvF, const uint2* __restrict__ qF,
    const uint4* __restrict__ gF,  const short* __restrict__ WoT,
    const float* __restrict__ bo,  float* __restrict__ out)
{
  __shared__ __align__(16) char sm[32768];     // GO tile: 64 rows x 256 bf16
  const int tid  = threadIdx.x;
  const int h    = tid >> 6;                   // wave = head
  const int lane = tid & 63;
  const int g = lane >> 4, c15 = lane & 15;
  const int blk = blockIdx.x;                  // 0..1023
  const int xcd = blk & 7, s8 = blk >> 3;
  const int r = xcd * 32 + (s8 >> 2), chq = s8 & 3;
  const int hbase = h * 32;
  const int ib = chq * 64;
  const f32x4 zz{0.f, 0.f, 0.f, 0.f};

  // ---- flash phase (identical math to r13/r14) ----
  bf16x8 bSq[4];
  #pragma unroll
  for (int nt = 0; nt < 4; nt++){
    const size_t qb = (((size_t)(r*8 + h)*16 + (ib >> 4) + nt)*2)*64 + lane;
    uint2 qlo = qF[qb], qhi = qF[qb + 64];
    bSq[nt] = mk_frag(qlo.x, qlo.y, qhi.x, qhi.y);
  }

  float l_[4];
  f32x4 o_[4][2];
  #pragma unroll
  for (int i2 = 0; i2 < 4; i2++){ l_[i2] = 0.f; o_[i2][0] = zz; o_[i2][1] = zz; }

  #pragma unroll 2
  for (int jt = 0; jt < 8; jt++){
    const size_t kb = ((size_t)(r*64 + h*8 + jt) * 4) * 64 + lane;
    const bf16x8 kf0 = __builtin_bit_cast(bf16x8, kvF[kb      ]);
    const bf16x8 kf1 = __builtin_bit_cast(bf16x8, kvF[kb +  64]);
    const bf16x8 vf0 = __builtin_bit_cast(bf16x8, kvF[kb + 128]);
    const bf16x8 vf1 = __builtin_bit_cast(bf16x8, kvF[kb + 192]);
    #pragma unroll
    for (int it = 0; it < 4; it++){
      f32x4 s0 = mfma16(kf0, bSq[it], zz);   // S[i=c15][j=32jt+4g+jj]
      f32x4 s1 = mfma16(kf1, bSq[it], zz);   // S[i=c15][j=32jt+16+4g+jj]
      float e0=exp2f(s0.x), e1=exp2f(s0.y), e2=exp2f(s0.z), e3=exp2f(s0.w);
      float e4=exp2f(s1.x), e5=exp2f(s1.y), e6=exp2f(s1.z), e7=exp2f(s1.w);
      l_[it] += ((e0+e1)+(e2+e3)) + ((e4+e5)+(e6+e7));
      bf16x8 aP = mk_frag(pk2(e0,e1), pk2(e2,e3), pk2(e4,e5), pk2(e6,e7));
      o_[it][0] = mfma16(aP, vf0, o_[it][0]);
      o_[it][1] = mfma16(aP, vf1, o_[it][1]);
    }
  }

  // ---- gate (f32 G), normalize, GO -> LDS (local rows 0..63) ----
  #pragma unroll
  for (int dr = 0; dr < 2; dr++){
    #pragma unroll
    for (int nt = 0; nt < 4; nt++){
      f32x4 ga = __builtin_bit_cast(f32x4,
          gF[(((size_t)(r*8 + h)*16 + (ib >> 4) + nt)*2 + dr)*64 + lane]);
      float lt = l_[nt];
      lt += __shfl_xor(lt, 16); lt += __shfl_xor(lt, 32);
      float inv[4];
      #pragma unroll
      for (int jj = 0; jj < 4; jj++) inv[jj] = 1.f / __shfl(lt, 4*g + jj);
      const f32x4 ov = o_[nt][dr];
      const unsigned w0 = pk2(ov[0]*inv[0]*ga.x, ov[1]*inv[1]*ga.y);
      const unsigned w1 = pk2(ov[2]*inv[2]*ga.z, ov[3]*inv[3]*ga.w);
      store_go(sm, nt*16 + 4*g, hbase + 16*dr + c15, w0, w1);
    }
  }
  __syncthreads();

  // ---- out-projection from LDS: wave -> (i-tile, 8 ct-tiles) ----
  const int it2 = h & 3;                       // local i-tile 0..3
  const int cth = (h >> 2) * 8;                // ct tiles 0..7 or 8..15
  bf16x8 aGO[8];
  #pragma unroll
  for (int kk = 0; kk < 8; kk++) aGO[kk] = lds_frag(sm, it2*16 + c15, 32*kk + 8*g);
  #pragma unroll 2
  for (int c8 = 0; c8 < 8; c8++){
    const int ct = cth + c8;
    f32x4 acc = zz;
    #pragma unroll
    for (int kk = 0; kk < 8; kk++)
      acc = mfma16(aGO[kk], ldg_frag(WoT, ct*16 + c15, 32*kk + 8*g), acc);
    const float bov = bo[ct*16 + c15];
    const int i0 = ib + it2*16 + g*4;
    const int cc = ct*16 + c15;
    out[(size_t)(i0 + 0) * 65536 + r * 256 + cc] = acc.x + bov;
    out[(size_t)(i0 + 1) * 65536 + r * 256 + cc] = acc.y + bov;
    out[(size_t)(i0 + 2) * 65536 + r * 256 + cc] = acc.z + bov;
    out[(size_t)(i0 + 3) * 65536 + r * 256 + cc] = acc.w + bov;
  }
}

// ---------------------------------------------------------------------------
extern "C" void kernel_launch(void* const* d_in, const int* in_sizes, int n_in,
                              void* d_out, int out_size, void* d_ws, size_t ws_size,
                              hipStream_t stream)
{
  (void)in_sizes; (void)n_in; (void)out_size; (void)ws_size;
  const float* msa = (const float*)d_in[0];
  const float* lnw = (const float*)d_in[1];
  const float* lnb = (const float*)d_in[2];
  const float* Wq  = (const float*)d_in[3];
  const float* Wk  = (const float*)d_in[4];
  const float* Wv  = (const float*)d_in[5];
  const float* Wg  = (const float*)d_in[6];
  const float* bg  = (const float*)d_in[7];
  const float* Wo  = (const float*)d_in[8];
  const float* bo  = (const float*)d_in[9];
  short* ws = (short*)d_ws;
  char* base = (char*)d_ws;

  prep_weights<<<256, 256, 0, stream>>>(Wq, Wk, Wv, Wg, Wo, ws);

  const size_t WB  = (size_t)5 * 65536 * 2;          //  0.66 MB weights
  const size_t KVB = (size_t)256*8*8*4*64 * 16;      // 67.11 MB K/V frags
  const size_t QB  = (size_t)256*8*16*2*64 * 8;      // 33.55 MB Q frags

  uint4* kvF = (uint4*)(base + WB);
  uint2* qF  = (uint2*)(base + WB + KVB);
  uint4* gF  = (uint4*)(base + WB + KVB + QB);
  msa_qkvg      <<<256, 512, 133120, stream>>>(msa, lnw, lnb, bg, ws, kvF, qF, gF);
  msa_flash_proj<<<1024, 512, 0, stream>>>(kvF, qF, gF, ws + 4*65536, bo, (float*)d_out);
}

// Round 20
// 179.827 us; speedup vs baseline: 1.4418x; 1.0006x over previous
//
#include <hip/hip_runtime.h>
#include <hip/hip_bf16.h>

// B=1, S=256 (attention/LN axis), R=256, C=256, H=8, D=32.
// Round 20: r16/r19 structure (best passing, 180 us) + two cliff-safe tweaks:
//  (1) gF stored as bf16 (uint2, 33.6 MB instead of f32 67.1 MB): cuts 33.6 MB
//      of qkvg writes + ~17 MB of flash fetch. Precedent: r2-r5 passed with a
//      bf16 gate; GO is bf16-quantized right after the gate multiply anyway.
//  (2) s_setprio(1) around the flash compute cluster (loads at prio 0): flash
//      waves are barrier-free/independent -> the regime where setprio helps
//      (guide m191, +4-7%). Pure scheduling hint, no numerics/codegen risk.
// Everything else byte-identical to round 19. All builtins, no inline asm.

using f32x4  = __attribute__((ext_vector_type(4))) float;
using bf16x8 = __attribute__((ext_vector_type(8))) short;

struct U4x { unsigned a0, a1, a2, a3; };
static_assert(sizeof(U4x) == sizeof(bf16x8), "frag size");

__device__ __forceinline__ f32x4 mfma16(bf16x8 a, bf16x8 b, f32x4 c){
  return __builtin_amdgcn_mfma_f32_16x16x32_bf16(a, b, c, 0, 0, 0);
}
// f32 -> bf16 RNE, finite inputs only.
__device__ __forceinline__ unsigned f2bf(float f){
  unsigned u = __builtin_bit_cast(unsigned, f);
  u += 0x7fffu + ((u >> 16) & 1u);
  return u >> 16;
}
__device__ __forceinline__ unsigned pk2(float lo, float hi){
  return f2bf(lo) | (f2bf(hi) << 16);
}
__device__ __forceinline__ float bf_lo(unsigned u){ return __builtin_bit_cast(float, u << 16); }
__device__ __forceinline__ float bf_hi(unsigned u){ return __builtin_bit_cast(float, u & 0xffff0000u); }
__device__ __forceinline__ bf16x8 mk_frag(unsigned a0, unsigned a1, unsigned a2, unsigned a3){
  U4x t{a0, a1, a2, a3};
  return __builtin_bit_cast(bf16x8, t);
}
__device__ __forceinline__ float sigm(float x){ return 1.f / (1.f + __expf(-x)); }

// Swizzled byte address in a [rows][256 bf16] LDS tile (row stride 512B).
__device__ __forceinline__ int xaddr(int row, int cbyte){
  return (row << 9) + (cbyte ^ ((row & 15) << 4));
}
__device__ __forceinline__ bf16x8 lds_frag(const char* sm, int row, int cshort){
  return *(const bf16x8*)(sm + xaddr(row, cshort * 2));
}
__device__ __forceinline__ bf16x8 ldg_frag(const short* base, int row, int cshort){
  return *(const bf16x8*)(base + row * 256 + cshort);
}
__device__ __forceinline__ void store_go(char* sm, int i0, int hd, unsigned v0, unsigned v1){
  *(short*)(sm + xaddr(i0 + 0, hd * 2)) = (short)(v0 & 0xffffu);
  *(short*)(sm + xaddr(i0 + 1, hd * 2)) = (short)(v0 >> 16);
  *(short*)(sm + xaddr(i0 + 2, hd * 2)) = (short)(v1 & 0xffffu);
  *(short*)(sm + xaddr(i0 + 3, hd * 2)) = (short)(v1 >> 16);
}

// ---------------- prep: transpose + bf16-convert the 5 weight matrices -----
// ws (shorts): WqT[256][256], WkT, WvT, WgT  (T[n][c] = W[c][n], n = h*32+d)
//              WoT[256][256]                 (WoT[c][hd] = Wo[hd][c])
__global__ __launch_bounds__(256) void prep_weights(
    const float* __restrict__ Wq, const float* __restrict__ Wk,
    const float* __restrict__ Wv, const float* __restrict__ Wg,
    const float* __restrict__ Wo, short* __restrict__ ws)
{
  const int n = blockIdx.x, t = threadIdx.x;
  ws[0*65536 + n*256 + t] = (short)f2bf(Wq[t*256 + n]);
  ws[1*65536 + n*256 + t] = (short)f2bf(Wk[t*256 + n]);
  ws[2*65536 + n*256 + t] = (short)f2bf(Wv[t*256 + n]);
  ws[3*65536 + n*256 + t] = (short)f2bf(Wg[t*256 + n]);
  ws[4*65536 + n*256 + t] = (short)f2bf(Wo[t*256 + n]);
}

// ---------------- phase 1: LN stats + normalized x tile (512 threads) ------
__device__ __forceinline__ void build_x_tile_512(
    char* sm, const float* msa_r, const float* lnw, const float* lnb, int tid)
{
  float* muA = (float*)(sm + 131072);
  float* rsA = muA + 256;
  {
    float s0 = 0.f, s1 = 0.f;
    const int c = tid & 255, sh = tid >> 8;
    const float* p = msa_r + (sh * 128) * 65536 + c;
    #pragma unroll 8
    for (int i = 0; i < 128; i++){ float v = p[i * 65536]; s0 += v; s1 += v * v; }
    float* sb = (float*)sm;
    sb[tid] = s0; sb[512 + tid] = s1;
    __syncthreads();
    if (tid < 256){
      float tot = sb[tid] + sb[256 + tid];
      float sq  = sb[512 + tid] + sb[768 + tid];
      float mu  = tot * (1.f / 256.f);
      float var = fmaxf(sq * (1.f / 256.f) - mu * mu, 0.f);
      muA[tid] = mu; rsA[tid] = rsqrtf(var + 1e-5f);
    }
    __syncthreads();
  }
  {
    const int c0 = (tid & 31) * 8;
    float mu0[8], rs0[8];
    #pragma unroll
    for (int k = 0; k < 8; k++){ mu0[k] = muA[c0 + k]; rs0[k] = rsA[c0 + k]; }
    for (int itr = 0; itr < 16; itr++){
      const int s = itr * 16 + (tid >> 5);
      const float w = lnw[s], b = lnb[s];
      const float* rp = msa_r + s * 65536 + c0;
      f32x4 v0 = *(const f32x4*)rp;
      f32x4 v1 = *(const f32x4*)(rp + 4);
      U4x q{pk2((v0.x-mu0[0])*rs0[0]*w+b, (v0.y-mu0[1])*rs0[1]*w+b),
            pk2((v0.z-mu0[2])*rs0[2]*w+b, (v0.w-mu0[3])*rs0[3]*w+b),
            pk2((v1.x-mu0[4])*rs0[4]*w+b, (v1.y-mu0[5])*rs0[5]*w+b),
            pk2((v1.z-mu0[6])*rs0[6]*w+b, (v1.w-mu0[7])*rs0[7]*w+b)};
      *(U4x*)(sm + xaddr(s, c0 * 2)) = q;
    }
    __syncthreads();
  }
}

// ---------------- stage 2: LN + QKVG fragment generation -------------------
// kvF: uint4 [r][head][jt(8)][4:{kf0,kf1,vf0,vf1}][lane]        (67.1 MB)
// qF : uint2 [r][head][it(16)][dr(2)][lane]                     (33.6 MB)
// gF : uint2 (bf16x4) [r][head][it(16)][dr(2)][lane]            (33.6 MB)
__global__ __launch_bounds__(512) void msa_qkvg(
    const float* __restrict__ msa, const float* __restrict__ lnw,
    const float* __restrict__ lnb, const float* __restrict__ bg,
    const short* __restrict__ wsW,
    uint4* __restrict__ kvF, uint2* __restrict__ qF, uint2* __restrict__ gF)
{
  extern __shared__ __align__(16) char sm[];
  const int r   = blockIdx.x;
  const int tid = threadIdx.x;
  build_x_tile_512(sm, msa + r * 256, lnw, lnb, tid);

  const int wid  = tid >> 6;                   // head
  const int lane = tid & 63;
  const int g = lane >> 4, c15 = lane & 15;
  const short* WqT = wsW;
  const short* WkT = wsW + 65536;
  const short* WvT = wsW + 2 * 65536;
  const short* WgT = wsW + 3 * 65536;
  const int hbase = wid * 32;
  const float bg0 = bg[hbase + c15], bg1 = bg[hbase + 16 + c15];
  const float scl = 0.17677669529663687f * 1.4426950408889634f; // /sqrt(32)*log2e
  const f32x4 zz{0.f, 0.f, 0.f, 0.f};

  // ---- K^T / V fragments per j-tile (accumulators die into stores) ----
  #pragma unroll 1
  for (int jt = 0; jt < 8; jt++){
    const int jb = jt * 32;
    f32x4 kt00=zz, kt01=zz, kt10=zz, kt11=zz;
    f32x4 va00=zz, va01=zz, va10=zz, va11=zz;
    #pragma unroll
    for (int kk = 0; kk < 8; kk++){
      const int cs = 32*kk + 8*g;
      bf16x8 wk0 = ldg_frag(WkT, hbase + c15,      cs);
      bf16x8 wk1 = ldg_frag(WkT, hbase + 16 + c15, cs);
      bf16x8 wv0 = ldg_frag(WvT, hbase + c15,      cs);
      bf16x8 wv1 = ldg_frag(WvT, hbase + 16 + c15, cs);
      bf16x8 bx0 = lds_frag(sm, jb + c15,      cs);
      bf16x8 bx1 = lds_frag(sm, jb + 16 + c15, cs);
      kt00 = mfma16(wk0, bx0, kt00);   // K^T[d 0:16 ][j 0:16 ]
      kt01 = mfma16(wk0, bx1, kt01);   // K^T[d 0:16 ][j 16:32]
      kt10 = mfma16(wk1, bx0, kt10);   // K^T[d 16:32][j 0:16 ]
      kt11 = mfma16(wk1, bx1, kt11);   // K^T[d 16:32][j 16:32]
      va00 = mfma16(bx0, wv0, va00);   // V[j 0:16 ][d 0:16 ]
      va01 = mfma16(bx0, wv1, va01);   // V[j 0:16 ][d 16:32]
      va10 = mfma16(bx1, wv0, va10);   // V[j 16:32][d 0:16 ]
      va11 = mfma16(bx1, wv1, va11);   // V[j 16:32][d 16:32]
    }
    const bf16x8 kf0 = mk_frag(pk2(kt00.x,kt00.y), pk2(kt00.z,kt00.w),
                               pk2(kt10.x,kt10.y), pk2(kt10.z,kt10.w));
    const bf16x8 kf1 = mk_frag(pk2(kt01.x,kt01.y), pk2(kt01.z,kt01.w),
                               pk2(kt11.x,kt11.y), pk2(kt11.z,kt11.w));
    const bf16x8 vf0 = mk_frag(pk2(va00.x,va00.y), pk2(va00.z,va00.w),
                               pk2(va10.x,va10.y), pk2(va10.z,va10.w));
    const bf16x8 vf1 = mk_frag(pk2(va01.x,va01.y), pk2(va01.z,va01.w),
                               pk2(va11.x,va11.y), pk2(va11.z,va11.w));
    const size_t kb = ((size_t)(r*64 + wid*8 + jt) * 4) * 64 + lane;
    kvF[kb      ] = __builtin_bit_cast(uint4, kf0);
    kvF[kb +  64] = __builtin_bit_cast(uint4, kf1);
    kvF[kb + 128] = __builtin_bit_cast(uint4, vf0);
    kvF[kb + 192] = __builtin_bit_cast(uint4, vf1);
  }

  // ---- Q^T fragments (scaled), per (dr, it) ----
  #pragma unroll 1
  for (int dr = 0; dr < 2; dr++){
    bf16x8 wq[8];
    #pragma unroll
    for (int kk = 0; kk < 8; kk++) wq[kk] = ldg_frag(WqT, hbase + 16*dr + c15, 32*kk + 8*g);
    #pragma unroll 1
    for (int it = 0; it < 16; it++){
      f32x4 a = zz;
      #pragma unroll
      for (int kk = 0; kk < 8; kk++)
        a = mfma16(wq[kk], lds_frag(sm, it*16 + c15, 32*kk + 8*g), a);
      uint2 qv; qv.x = pk2(a.x*scl, a.y*scl); qv.y = pk2(a.z*scl, a.w*scl);
      qF[(((size_t)(r*8 + wid)*16 + it)*2 + dr)*64 + lane] = qv;
    }
  }

  // ---- G fragments (sigmoid applied, packed bf16) ----
  #pragma unroll 1
  for (int dr = 0; dr < 2; dr++){
    bf16x8 wg[8];
    #pragma unroll
    for (int kk = 0; kk < 8; kk++) wg[kk] = ldg_frag(WgT, hbase + 16*dr + c15, 32*kk + 8*g);
    const float bgd = dr ? bg1 : bg0;
    #pragma unroll 1
    for (int it = 0; it < 16; it++){
      f32x4 a = zz;
      #pragma unroll
      for (int kk = 0; kk < 8; kk++)
        a = mfma16(lds_frag(sm, it*16 + c15, 32*kk + 8*g), wg[kk], a);
      uint2 gv;
      gv.x = pk2(sigm(a.x + bgd), sigm(a.y + bgd));
      gv.y = pk2(sigm(a.z + bgd), sigm(a.w + bgd));
      gF[(((size_t)(r*8 + wid)*16 + it)*2 + dr)*64 + lane] = gv;
    }
  }
}

// ---------------- stage 3: flash + gate + out-projection (fused) -----------
// XCD-aware mapping: xcd = blk&7, s = blk>>3 -> r = xcd*32 + (s>>2), chq=s&3.
// All 4 chq-blocks of an r share blockIdx mod 8 -> same XCD -> kvF L2-hot.
__global__ __launch_bounds__(512) void msa_flash_proj(
    const uint4* __restrict__ kvF, const uint2* __restrict__ qF,
    const uint2* __restrict__ gF,  const short* __restrict__ WoT,
    const float* __restrict__ bo,  float* __restrict__ out)
{
  __shared__ __align__(16) char sm[32768];     // GO tile: 64 rows x 256 bf16
  const int tid  = threadIdx.x;
  const int h    = tid >> 6;                   // wave = head
  const int lane = tid & 63;
  const int g = lane >> 4, c15 = lane & 15;
  const int blk = blockIdx.x;                  // 0..1023
  const int xcd = blk & 7, s8 = blk >> 3;
  const int r = xcd * 32 + (s8 >> 2), chq = s8 & 3;
  const int hbase = h * 32;
  const int ib = chq * 64;
  const f32x4 zz{0.f, 0.f, 0.f, 0.f};

  // ---- flash phase ----
  bf16x8 bSq[4];
  #pragma unroll
  for (int nt = 0; nt < 4; nt++){
    const size_t qb = (((size_t)(r*8 + h)*16 + (ib >> 4) + nt)*2)*64 + lane;
    uint2 qlo = qF[qb], qhi = qF[qb + 64];
    bSq[nt] = mk_frag(qlo.x, qlo.y, qhi.x, qhi.y);
  }

  float l_[4];
  f32x4 o_[4][2];
  #pragma unroll
  for (int i2 = 0; i2 < 4; i2++){ l_[i2] = 0.f; o_[i2][0] = zz; o_[i2][1] = zz; }

  #pragma unroll 2
  for (int jt = 0; jt < 8; jt++){
    const size_t kb = ((size_t)(r*64 + h*8 + jt) * 4) * 64 + lane;
    const bf16x8 kf0 = __builtin_bit_cast(bf16x8, kvF[kb      ]);
    const bf16x8 kf1 = __builtin_bit_cast(bf16x8, kvF[kb +  64]);
    const bf16x8 vf0 = __builtin_bit_cast(bf16x8, kvF[kb + 128]);
    const bf16x8 vf1 = __builtin_bit_cast(bf16x8, kvF[kb + 192]);
    // compute cluster at raised priority: waves mid-compute get the SIMD
    // ahead of waves still issuing their kvF loads (T5 regime: no barriers).
    __builtin_amdgcn_s_setprio(1);
    #pragma unroll
    for (int it = 0; it < 4; it++){
      f32x4 s0 = mfma16(kf0, bSq[it], zz);   // S[i=c15][j=32jt+4g+jj]
      f32x4 s1 = mfma16(kf1, bSq[it], zz);   // S[i=c15][j=32jt+16+4g+jj]
      float e0=exp2f(s0.x), e1=exp2f(s0.y), e2=exp2f(s0.z), e3=exp2f(s0.w);
      float e4=exp2f(s1.x), e5=exp2f(s1.y), e6=exp2f(s1.z), e7=exp2f(s1.w);
      l_[it] += ((e0+e1)+(e2+e3)) + ((e4+e5)+(e6+e7));
      bf16x8 aP = mk_frag(pk2(e0,e1), pk2(e2,e3), pk2(e4,e5), pk2(e6,e7));
      o_[it][0] = mfma16(aP, vf0, o_[it][0]);
      o_[it][1] = mfma16(aP, vf1, o_[it][1]);
    }
    __builtin_amdgcn_s_setprio(0);
  }

  // ---- gate (bf16 G), normalize, GO -> LDS (local rows 0..63) ----
  #pragma unroll
  for (int dr = 0; dr < 2; dr++){
    #pragma unroll
    for (int nt = 0; nt < 4; nt++){
      const uint2 gu = gF[(((size_t)(r*8 + h)*16 + (ib >> 4) + nt)*2 + dr)*64 + lane];
      const float gax = bf_lo(gu.x), gay = bf_hi(gu.x);
      const float gaz = bf_lo(gu.y), gaw = bf_hi(gu.y);
      float lt = l_[nt];
      lt += __shfl_xor(lt, 16); lt += __shfl_xor(lt, 32);
      float inv[4];
      #pragma unroll
      for (int jj = 0; jj < 4; jj++) inv[jj] = 1.f / __shfl(lt, 4*g + jj);
      const f32x4 ov = o_[nt][dr];
      const unsigned w0 = pk2(ov[0]*inv[0]*gax, ov[1]*inv[1]*gay);
      const unsigned w1 = pk2(ov[2]*inv[2]*gaz, ov[3]*inv[3]*gaw);
      store_go(sm, nt*16 + 4*g, hbase + 16*dr + c15, w0, w1);
    }
  }
  __syncthreads();

  // ---- out-projection from LDS: wave -> (i-tile, 8 ct-tiles) ----
  const int it2 = h & 3;                       // local i-tile 0..3
  const int cth = (h >> 2) * 8;                // ct tiles 0..7 or 8..15
  bf16x8 aGO[8];
  #pragma unroll
  for (int kk = 0; kk < 8; kk++) aGO[kk] = lds_frag(sm, it2*16 + c15, 32*kk + 8*g);
  #pragma unroll 2
  for (int c8 = 0; c8 < 8; c8++){
    const int ct = cth + c8;
    f32x4 acc = zz;
    #pragma unroll
    for (int kk = 0; kk < 8; kk++)
      acc = mfma16(aGO[kk], ldg_frag(WoT, ct*16 + c15, 32*kk + 8*g), acc);
    const float bov = bo[ct*16 + c15];
    const int i0 = ib + it2*16 + g*4;
    const int cc = ct*16 + c15;
    out[(size_t)(i0 + 0) * 65536 + r * 256 + cc] = acc.x + bov;
    out[(size_t)(i0 + 1) * 65536 + r * 256 + cc] = acc.y + bov;
    out[(size_t)(i0 + 2) * 65536 + r * 256 + cc] = acc.z + bov;
    out[(size_t)(i0 + 3) * 65536 + r * 256 + cc] = acc.w + bov;
  }
}

// ---------------------------------------------------------------------------
extern "C" void kernel_launch(void* const* d_in, const int* in_sizes, int n_in,
                              void* d_out, int out_size, void* d_ws, size_t ws_size,
                              hipStream_t stream)
{
  (void)in_sizes; (void)n_in; (void)out_size; (void)ws_size;
  const float* msa = (const float*)d_in[0];
  const float* lnw = (const float*)d_in[1];
  const float* lnb = (const float*)d_in[2];
  const float* Wq  = (const float*)d_in[3];
  const float* Wk  = (const float*)d_in[4];
  const float* Wv  = (const float*)d_in[5];
  const float* Wg  = (const float*)d_in[6];
  const float* bg  = (const float*)d_in[7];
  const float* Wo  = (const float*)d_in[8];
  const float* bo  = (const float*)d_in[9];
  short* ws = (short*)d_ws;
  char* base = (char*)d_ws;

  prep_weights<<<256, 256, 0, stream>>>(Wq, Wk, Wv, Wg, Wo, ws);

  const size_t WB  = (size_t)5 * 65536 * 2;          //  0.66 MB weights
  const size_t KVB = (size_t)256*8*8*4*64 * 16;      // 67.11 MB K/V frags
  const size_t QB  = (size_t)256*8*16*2*64 * 8;      // 33.55 MB Q frags

  uint4* kvF = (uint4*)(base + WB);
  uint2* qF  = (uint2*)(base + WB + KVB);
  uint2* gF  = (uint2*)(base + WB + KVB + QB);       // 33.55 MB bf16 G frags
  msa_qkvg      <<<256, 512, 133120, stream>>>(msa, lnw, lnb, bg, ws, kvF, qF, gF);
  msa_flash_proj<<<1024, 512, 0, stream>>>(kvF, qF, gF, ws + 4*65536, bo, (float*)d_out);
}